// Round 11
// baseline (86.509 us; speedup 1.0000x reference)
//
#include <hip/hip_runtime.h>
#include <hip/hip_bf16.h>

#define ALPHA 100.0f

typedef float v2f __attribute__((ext_vector_type(2)));

// Per-triangle precomputed invariants: 6 x float4 = 96 B
//  q0: v0.xyz, dt   q1: e0.xyz, dot00   q2: e1.xyz, dot11
//  q3: nn.xyz, dot01 (nn = n * rsqrt(denom))
//  q4: inv00, inv11, c12, invab   q5: abab, -, -, -
__global__ __launch_bounds__(256) void rast_pre(const float* __restrict__ tv,
                                                float4* __restrict__ pre) {
    int i = blockIdx.x * 256 + threadIdx.x;   // 0..4095
    if (i >= 4096) return;
    const float* t = tv + (size_t)i * 9;
    float v0x = t[0], v0y = t[1], v0z = t[2];
    float v1x = t[3], v1y = t[4], v1z = t[5];
    float v2x = t[6], v2y = t[7], v2z = t[8];

    float e0x = v1x - v0x, e0y = v1y - v0y, e0z = v1z - v0z;
    float e1x = v2x - v0x, e1y = v2y - v0y, e1z = v2z - v0z;

    float nx = e0y * e1z - e0z * e1y;
    float ny = e0z * e1x - e0x * e1z;
    float nz = e0x * e1y - e0y * e1x;
    float area2 = nx * nx + ny * ny + nz * nz;

    float dot00 = e0x * e0x + e0y * e0y + e0z * e0z;
    float dot01 = e0x * e1x + e0y * e1y + e0z * e1z;
    float dot11 = e1x * e1x + e1y * e1y + e1z * e1z;

    float denom = fmaxf(area2, 1e-12f);
    double rs   = 1.0 / sqrt((double)denom);
    float nnx = (float)(nx * rs), nny = (float)(ny * rs), nnz = (float)(nz * rs);

    float inv00 = 1.0f / fmaxf(dot00, 1e-12f);
    float inv11 = 1.0f / fmaxf(dot11, 1e-12f);
    float abab  = dot00 - 2.0f * dot01 + dot11;
    float invab = 1.0f / fmaxf(abab, 1e-12f);
    float dt    = (area2 >= 4e-10f) ? denom : -1.0f;
    float c12   = dot00 - dot01;

    float4* q = pre + (size_t)i * 6;
    q[0] = make_float4(v0x, v0y, v0z, dt);
    q[1] = make_float4(e0x, e0y, e0z, dot00);
    q[2] = make_float4(e1x, e1y, e1z, dot11);
    q[3] = make_float4(nnx, nny, nnz, dot01);
    q[4] = make_float4(inv00, inv11, c12, invab);
    q[5] = make_float4(abab, 0.0f, 0.0f, 0.0f);
}

// Two triangles packed as float2 halves (halves instruction count; FLOP rate same).
struct TP {
    v2f v0x, v0y, v0z, dt;
    v2f e0x, e0y, e0z, d00;
    v2f e1x, e1y, e1z, d11;
    v2f nnx, nny, nnz, d01;
    v2f i00, i11, c12, iab;
    v2f ab;
};

__device__ __forceinline__ void load_pair(const float4* __restrict__ p6,
                                          int ta, int tb, TP& t) {
    const float4* qa = p6 + (size_t)ta * 6;
    const float4* qb = p6 + (size_t)tb * 6;
    float4 a0 = qa[0], a1 = qa[1], a2 = qa[2], a3 = qa[3], a4 = qa[4], a5 = qa[5];
    float4 b0 = qb[0], b1 = qb[1], b2 = qb[2], b3 = qb[3], b4 = qb[4], b5 = qb[5];
    t.v0x = (v2f){a0.x, b0.x}; t.v0y = (v2f){a0.y, b0.y}; t.v0z = (v2f){a0.z, b0.z}; t.dt  = (v2f){a0.w, b0.w};
    t.e0x = (v2f){a1.x, b1.x}; t.e0y = (v2f){a1.y, b1.y}; t.e0z = (v2f){a1.z, b1.z}; t.d00 = (v2f){a1.w, b1.w};
    t.e1x = (v2f){a2.x, b2.x}; t.e1y = (v2f){a2.y, b2.y}; t.e1z = (v2f){a2.z, b2.z}; t.d11 = (v2f){a2.w, b2.w};
    t.nnx = (v2f){a3.x, b3.x}; t.nny = (v2f){a3.y, b3.y}; t.nnz = (v2f){a3.z, b3.z}; t.d01 = (v2f){a3.w, b3.w};
    t.i00 = (v2f){a4.x, b4.x}; t.i11 = (v2f){a4.y, b4.y}; t.c12 = (v2f){a4.z, b4.z}; t.iab = (v2f){a4.w, b4.w};
    t.ab  = (v2f){a5.x, b5.x};
}

// point (block-uniform scalars -> SGPRs) vs 2 packed triangles; returns updated min
__device__ __forceinline__ float pair_min(float px, float py, float pz,
                                          const TP& g, float prev) {
    v2f dx = px - g.v0x, dy = py - g.v0y, dz = pz - g.v0z;
    v2f dd = dx * dx + dy * dy + dz * dz;
    v2f a0 = g.e0x * dx + g.e0y * dy + g.e0z * dz;
    v2f a1 = g.e1x * dx + g.e1y * dy + g.e1z * dz;
    v2f dn = g.nnx * dx + g.nny * dy + g.nnz * dz;

    v2f U = g.d11 * a0 - g.d01 * a1;
    v2f V = g.d00 * a1 - g.d01 * a0;
    v2f W = g.dt - (U + V);
    v2f plane = dn * dn;

    v2f a02 = a0 + a0;
    v2f m1 = a0 * g.i00;
    v2f t1; t1.x = fminf(fmaxf(m1.x, 0.f), 1.f); t1.y = fminf(fmaxf(m1.y, 0.f), 1.f);
    v2f s1 = dd + t1 * (t1 * g.d00 - a02);
    v2f a12 = a1 + a1;
    v2f m2 = a1 * g.i11;
    v2f t2; t2.x = fminf(fmaxf(m2.x, 0.f), 1.f); t2.y = fminf(fmaxf(m2.y, 0.f), 1.f);
    v2f s2 = dd + t2 * (t2 * g.d11 - a12);
    v2f pab  = (g.c12 + a1) - a0;
    v2f papa = (dd - a02) + g.d00;
    v2f m3 = pab * g.iab;
    v2f t3; t3.x = fminf(fmaxf(m3.x, 0.f), 1.f); t3.y = fminf(fmaxf(m3.y, 0.f), 1.f);
    v2f s3 = papa + t3 * (t3 * g.ab - (pab + pab));

    float ex = fminf(fminf(s1.x, s2.x), s3.x);           // v_min3
    float ey = fminf(fminf(s1.y, s2.y), s3.y);
    float ix = fminf(fminf(U.x, V.x), W.x);              // v_min3
    float iy = fminf(fminf(U.y, V.y), W.y);
    float rx = (ix >= 0.f) ? plane.x : ex;
    float ry = (iy >= 0.f) ? plane.y : ey;
    return fminf(fminf(rx, ry), prev);                   // v_min3
}

// Grid: 2048 blocks x 256 threads (4 waves), launch_bounds(256,5) -> VGPR<=102,
// 5 blocks/CU = 5 waves/SIMD.
// block -> (batch = blk>>9, point-group = blk&511 -> 16 points).
// 16 points = 48 block-uniform floats -> ALL fit in SGPRs (no scalar-side spill,
// unlike the 32-point/96-float variant). Each lane covers 4 triangles via 2 rounds
// of a 2-packed TP register load; body is pure VALU.
__global__ __launch_bounds__(256, 5) void rast_main(const float* __restrict__ pts,
                                                    const float4* __restrict__ pre,
                                                    float* __restrict__ out) {
    int blk  = blockIdx.x;
    int b    = blk >> 9;          // batch
    int pg   = blk & 511;         // point group of 16
    int base = (b << 13) + (pg << 4);
    int t    = threadIdx.x;
    int lane = t & 63;
    int wave = __builtin_amdgcn_readfirstlane(t >> 6);   // 0..3

    const float4* p6 = pre + (size_t)b * 1024 * 6;
    const float* sp = pts + (size_t)base * 3;   // 48 floats, block-uniform -> s_load

    float M[16];
#pragma unroll
    for (int j = 0; j < 16; ++j) M[j] = 3.4e38f;

#pragma unroll
    for (int r = 0; r < 2; ++r) {
        int ta = r * 512 + wave * 128 + lane;
        TP g0;
        load_pair(p6, ta, ta + 64, g0);
#pragma unroll
        for (int j = 0; j < 16; ++j) {
            M[j] = pair_min(sp[j * 3 + 0], sp[j * 3 + 1], sp[j * 3 + 2], g0, M[j]);
        }
    }

    // --- block reduce: min over 256 threads for each of 16 points ---
    __shared__ float red[256 * 17];      // padded stride 17 -> conflict-free, 17.4 KB
    __shared__ float part[256];
#pragma unroll
    for (int j = 0; j < 16; ++j) red[t * 17 + j] = M[j];
    __syncthreads();
    int p = t & 15, g = t >> 4;          // 16 groups x 16 source-threads
    float m = 3.4e38f;
#pragma unroll
    for (int s = 0; s < 16; ++s) m = fminf(m, red[(g * 16 + s) * 17 + p]);
    part[t] = m;
    __syncthreads();
    if (t < 16) {
        float mm = part[t];
#pragma unroll
        for (int g2 = 1; g2 < 16; ++g2) mm = fminf(mm, part[g2 * 16 + t]);
        out[base + t] = __expf(-ALPHA * mm);
    }
}

extern "C" void kernel_launch(void* const* d_in, const int* in_sizes, int n_in,
                              void* d_out, int out_size, void* d_ws, size_t ws_size,
                              hipStream_t stream) {
    const float* pts = (const float*)d_in[0];   // (4, 8192, 3)
    const float* tv  = (const float*)d_in[1];   // (4, 1024, 3, 3)
    float* out = (float*)d_out;                 // (4, 8192)
    float4* pre = (float4*)d_ws;                // 4096 * 6 float4 = 384 KB

    rast_pre<<<16, 256, 0, stream>>>(tv, pre);
    rast_main<<<2048, 256, 0, stream>>>(pts, pre, out);
}

// Round 12
// 86.326 us; speedup vs baseline: 1.0021x; 1.0021x over previous
//
#include <hip/hip_runtime.h>
#include <hip/hip_bf16.h>

#define ALPHA 100.0f

typedef float v2f __attribute__((ext_vector_type(2)));

// Per-triangle precomputed invariants: 6 x float4 = 96 B
//  q0: v0.xyz, dt   q1: e0.xyz, dot00   q2: e1.xyz, dot11
//  q3: nn.xyz, dot01 (nn = n * rsqrt(denom))
//  q4: inv00, inv11, c12, invab   q5: abab, -, -, -
__global__ __launch_bounds__(256) void rast_pre(const float* __restrict__ tv,
                                                float4* __restrict__ pre) {
    int i = blockIdx.x * 256 + threadIdx.x;   // 0..4095
    if (i >= 4096) return;
    const float* t = tv + (size_t)i * 9;
    float v0x = t[0], v0y = t[1], v0z = t[2];
    float v1x = t[3], v1y = t[4], v1z = t[5];
    float v2x = t[6], v2y = t[7], v2z = t[8];

    float e0x = v1x - v0x, e0y = v1y - v0y, e0z = v1z - v0z;
    float e1x = v2x - v0x, e1y = v2y - v0y, e1z = v2z - v0z;

    float nx = e0y * e1z - e0z * e1y;
    float ny = e0z * e1x - e0x * e1z;
    float nz = e0x * e1y - e0y * e1x;
    float area2 = nx * nx + ny * ny + nz * nz;

    float dot00 = e0x * e0x + e0y * e0y + e0z * e0z;
    float dot01 = e0x * e1x + e0y * e1y + e0z * e1z;
    float dot11 = e1x * e1x + e1y * e1y + e1z * e1z;

    float denom = fmaxf(area2, 1e-12f);
    double rs   = 1.0 / sqrt((double)denom);
    float nnx = (float)(nx * rs), nny = (float)(ny * rs), nnz = (float)(nz * rs);

    float inv00 = 1.0f / fmaxf(dot00, 1e-12f);
    float inv11 = 1.0f / fmaxf(dot11, 1e-12f);
    float abab  = dot00 - 2.0f * dot01 + dot11;
    float invab = 1.0f / fmaxf(abab, 1e-12f);
    float dt    = (area2 >= 4e-10f) ? denom : -1.0f;
    float c12   = dot00 - dot01;

    float4* q = pre + (size_t)i * 6;
    q[0] = make_float4(v0x, v0y, v0z, dt);
    q[1] = make_float4(e0x, e0y, e0z, dot00);
    q[2] = make_float4(e1x, e1y, e1z, dot11);
    q[3] = make_float4(nnx, nny, nnz, dot01);
    q[4] = make_float4(inv00, inv11, c12, invab);
    q[5] = make_float4(abab, 0.0f, 0.0f, 0.0f);
}

// Two triangles packed as float2 halves (halves instruction count; FLOP rate same).
struct TP {
    v2f v0x, v0y, v0z, dt;
    v2f e0x, e0y, e0z, d00;
    v2f e1x, e1y, e1z, d11;
    v2f nnx, nny, nnz, d01;
    v2f i00, i11, c12, iab;
    v2f ab;
};

__device__ __forceinline__ void load_pair(const float4* __restrict__ p6,
                                          int ta, int tb, TP& t) {
    const float4* qa = p6 + (size_t)ta * 6;
    const float4* qb = p6 + (size_t)tb * 6;
    float4 a0 = qa[0], a1 = qa[1], a2 = qa[2], a3 = qa[3], a4 = qa[4], a5 = qa[5];
    float4 b0 = qb[0], b1 = qb[1], b2 = qb[2], b3 = qb[3], b4 = qb[4], b5 = qb[5];
    t.v0x = (v2f){a0.x, b0.x}; t.v0y = (v2f){a0.y, b0.y}; t.v0z = (v2f){a0.z, b0.z}; t.dt  = (v2f){a0.w, b0.w};
    t.e0x = (v2f){a1.x, b1.x}; t.e0y = (v2f){a1.y, b1.y}; t.e0z = (v2f){a1.z, b1.z}; t.d00 = (v2f){a1.w, b1.w};
    t.e1x = (v2f){a2.x, b2.x}; t.e1y = (v2f){a2.y, b2.y}; t.e1z = (v2f){a2.z, b2.z}; t.d11 = (v2f){a2.w, b2.w};
    t.nnx = (v2f){a3.x, b3.x}; t.nny = (v2f){a3.y, b3.y}; t.nnz = (v2f){a3.z, b3.z}; t.d01 = (v2f){a3.w, b3.w};
    t.i00 = (v2f){a4.x, b4.x}; t.i11 = (v2f){a4.y, b4.y}; t.c12 = (v2f){a4.z, b4.z}; t.iab = (v2f){a4.w, b4.w};
    t.ab  = (v2f){a5.x, b5.x};
}

// point vs 2 packed triangles; returns updated running min
__device__ __forceinline__ float pair_min(float px, float py, float pz,
                                          const TP& g, float prev) {
    v2f dx = px - g.v0x, dy = py - g.v0y, dz = pz - g.v0z;
    v2f dd = dx * dx + dy * dy + dz * dz;
    v2f a0 = g.e0x * dx + g.e0y * dy + g.e0z * dz;
    v2f a1 = g.e1x * dx + g.e1y * dy + g.e1z * dz;
    v2f dn = g.nnx * dx + g.nny * dy + g.nnz * dz;

    v2f U = g.d11 * a0 - g.d01 * a1;
    v2f V = g.d00 * a1 - g.d01 * a0;
    v2f W = g.dt - (U + V);
    v2f plane = dn * dn;

    v2f a02 = a0 + a0;
    v2f m1 = a0 * g.i00;
    v2f t1; t1.x = fminf(fmaxf(m1.x, 0.f), 1.f); t1.y = fminf(fmaxf(m1.y, 0.f), 1.f);
    v2f s1 = dd + t1 * (t1 * g.d00 - a02);
    v2f a12 = a1 + a1;
    v2f m2 = a1 * g.i11;
    v2f t2; t2.x = fminf(fmaxf(m2.x, 0.f), 1.f); t2.y = fminf(fmaxf(m2.y, 0.f), 1.f);
    v2f s2 = dd + t2 * (t2 * g.d11 - a12);
    v2f pab  = (g.c12 + a1) - a0;
    v2f papa = (dd - a02) + g.d00;
    v2f m3 = pab * g.iab;
    v2f t3; t3.x = fminf(fmaxf(m3.x, 0.f), 1.f); t3.y = fminf(fmaxf(m3.y, 0.f), 1.f);
    v2f s3 = papa + t3 * (t3 * g.ab - (pab + pab));

    float ex = fminf(fminf(s1.x, s2.x), s3.x);           // v_min3
    float ey = fminf(fminf(s1.y, s2.y), s3.y);
    float ix = fminf(fminf(U.x, V.x), W.x);              // v_min3
    float iy = fminf(fminf(U.y, V.y), W.y);
    float rx = (ix >= 0.f) ? plane.x : ex;
    float ry = (iy >= 0.f) ? plane.y : ey;
    return fminf(fminf(rx, ry), prev);                   // v_min3
}

// Grid: 2048 blocks x 256 threads (4 waves), launch_bounds(256,4) -> VGPR<=128.
// block -> (batch = blk>>9, point-group = blk&511 -> 16 points).
// Lane holds 4 triangles as TWO live packed TPs (84 VGPR). The point loop is
// ROLLED (#pragma unroll 2): per point j, one uniform ds_read_b128 broadcast of
// the point, ~110-instr pure-VALU body, one ds_write of the lane's 4-tri min
// into the padded reduction tile. No M[] array, ~1 KB hot-loop code (I$-resident),
// minimal regalloc pressure -- this is the A/B against the fully-unrolled variants.
__global__ __launch_bounds__(256, 4) void rast_main(const float* __restrict__ pts,
                                                    const float4* __restrict__ pre,
                                                    float* __restrict__ out) {
    int blk  = blockIdx.x;
    int b    = blk >> 9;          // batch
    int pg   = blk & 511;         // point group of 16
    int base = (b << 13) + (pg << 4);
    int t    = threadIdx.x;
    int lane = t & 63;
    int wave = __builtin_amdgcn_readfirstlane(t >> 6);   // 0..3

    const float4* p6 = pre + (size_t)b * 1024 * 6;
    int ta = wave * 128 + lane;

    TP g0, g1;
    load_pair(p6, ta,       ta + 64,  g0);
    load_pair(p6, ta + 512, ta + 576, g1);

    __shared__ float4 sp4[16];           // points of this group, float4-padded
    __shared__ float  red[256 * 17];     // padded stride 17 -> conflict-free
    __shared__ float  part[256];

    if (t < 16) {
        const float* pp = pts + (size_t)(base + t) * 3;
        sp4[t] = make_float4(pp[0], pp[1], pp[2], 0.0f);
    }
    __syncthreads();

    int ra = t * 17;
#pragma unroll 2
    for (int j = 0; j < 16; ++j) {
        float4 p = sp4[j];               // uniform address -> LDS broadcast
        float m = pair_min(p.x, p.y, p.z, g0, 3.4e38f);
        m       = pair_min(p.x, p.y, p.z, g1, m);
        red[ra + j] = m;
    }
    __syncthreads();

    // --- block reduce: min over 256 threads for each of 16 points ---
    int p = t & 15, g = t >> 4;          // 16 groups x 16 source-threads
    float m = 3.4e38f;
#pragma unroll
    for (int s = 0; s < 16; ++s) m = fminf(m, red[(g * 16 + s) * 17 + p]);
    part[t] = m;
    __syncthreads();
    if (t < 16) {
        float mm = part[t];
#pragma unroll
        for (int g2 = 1; g2 < 16; ++g2) mm = fminf(mm, part[g2 * 16 + t]);
        out[base + t] = __expf(-ALPHA * mm);
    }
}

extern "C" void kernel_launch(void* const* d_in, const int* in_sizes, int n_in,
                              void* d_out, int out_size, void* d_ws, size_t ws_size,
                              hipStream_t stream) {
    const float* pts = (const float*)d_in[0];   // (4, 8192, 3)
    const float* tv  = (const float*)d_in[1];   // (4, 1024, 3, 3)
    float* out = (float*)d_out;                 // (4, 8192)
    float4* pre = (float4*)d_ws;                // 4096 * 6 float4 = 384 KB

    rast_pre<<<16, 256, 0, stream>>>(tv, pre);
    rast_main<<<2048, 256, 0, stream>>>(pts, pre, out);
}